// Round 2
// baseline (132.668 us; speedup 1.0000x reference)
//
#include <hip/hip_runtime.h>

// LayerStacks, bucket-sorted version.
// Samples are pre-sorted by bucket into a permutation in d_ws; each block of
// 1024 threads then spans at most 2 buckets, stages only those 2 weight sets
// (36.6 KB LDS -> 2 blocks/CU -> 8 waves/SIMD), and all weight ds_reads are
// wave-uniform -> LDS broadcast (no serialization).
#define NB 6
#define BSTR 4580        // per-slot stride; 4580 % 32 == 4 -> slots in distinct bank groups
#define O_W1B  0         // 8 rows x 132 (cols 0..128 valid)
#define O_W1PA 1056      // 8 rows x 132
#define O_W2   2112      // 64 x 32
#define O_WOUT 4160      // 320
#define O_B1B  4480      // 8
#define O_B1PA 4488      // 8
#define O_B2   4496      // 64
#define O_BOUT 4560      // 1

// ---------------- sort passes ------------------------------------------------
// ws int layout: [0..6) cnt, [8..14) cursor, [16..16+B) perm
__global__ void k_zero(int* ws) {
    if (threadIdx.x < 16) ws[threadIdx.x] = 0;
}

__global__ __launch_bounds__(1024) void k_hist(const int* __restrict__ ply,
                                               int* __restrict__ ws, int B) {
    __shared__ int lh[NB];
    const int tid = threadIdx.x;
    if (tid < NB) lh[tid] = 0;
    __syncthreads();
    const int s = blockIdx.x * 1024 + tid;
    if (s < B) atomicAdd(&lh[ply[s] / 10], 1);
    __syncthreads();
    if (tid < NB) atomicAdd(&ws[tid], lh[tid]);
}

__global__ void k_scan(int* ws) {
    if (threadIdx.x == 0) {
        int base = 0;
        for (int b = 0; b < NB; ++b) { ws[8 + b] = base; base += ws[b]; }
    }
}

__global__ __launch_bounds__(1024) void k_scatter(const int* __restrict__ ply,
                                                  int* __restrict__ ws, int B) {
    __shared__ int lh[NB];
    __shared__ int lbase[NB];
    int* cursor = ws + 8;
    int* perm   = ws + 16;
    const int tid = threadIdx.x;
    if (tid < NB) lh[tid] = 0;
    __syncthreads();
    const int s = blockIdx.x * 1024 + tid;
    int b = 0, lpos = 0;
    if (s < B) { b = ply[s] / 10; lpos = atomicAdd(&lh[b], 1); }
    __syncthreads();
    if (tid < NB) lbase[tid] = atomicAdd(&cursor[tid], lh[tid]);
    __syncthreads();
    if (s < B) perm[lbase[b] + lpos] = s;
}

// ---------------- staging helper --------------------------------------------
__device__ __forceinline__ void stage_bucket(float* __restrict__ dst, int bb, int tid,
                                             const float* __restrict__ W1b,
                                             const float* __restrict__ b1b,
                                             const float* __restrict__ W1pa,
                                             const float* __restrict__ b1pa,
                                             const float* __restrict__ W2,
                                             const float* __restrict__ b2,
                                             const float* __restrict__ Wout,
                                             const float* __restrict__ bout) {
    const float* w1b = W1b + bb * 1032;
    for (int e = tid; e < 1032; e += 1024) {
        int row = e / 129, col = e - row * 129;
        dst[O_W1B + row * 132 + col] = w1b[e];
    }
    const float* w1pa = W1pa + bb * 1032;
    for (int e = tid; e < 1032; e += 1024) {
        int row = e / 129, col = e - row * 129;
        dst[O_W1PA + row * 132 + col] = w1pa[e];
    }
    const float* w2 = W2 + bb * 2048;
    for (int e = tid; e < 2048; e += 1024) dst[O_W2 + e] = w2[e];
    if (tid < 320) dst[O_WOUT + tid] = Wout[bb * 320 + tid];
    if (tid >= 512 && tid < 520) dst[O_B1B + tid - 512] = b1b[bb * 8 + tid - 512];
    if (tid >= 544 && tid < 552) dst[O_B1PA + tid - 544] = b1pa[bb * 8 + tid - 544];
    if (tid >= 576 && tid < 640) dst[O_B2 + tid - 576] = b2[bb * 64 + tid - 576];
    if (tid == 704) dst[O_BOUT] = bout[bb];
}

// ---------------- per-sample compute core -----------------------------------
__device__ __forceinline__ float compute_sample(const float* __restrict__ bk,
                                                const float* __restrict__ x_base,
                                                const float* __restrict__ x_pa,
                                                float mob, int s) {
    float acc1[16];
    #pragma unroll
    for (int j = 0; j < 8; ++j)
        acc1[j] = bk[O_B1B + j] + bk[O_W1B + j * 132 + 128] * mob;
    #pragma unroll
    for (int j = 0; j < 8; ++j)
        acc1[8 + j] = bk[O_B1PA + j] + bk[O_W1PA + j * 132 + 128] * mob;

    float accout = bk[O_BOUT];

    const float4* xb4 = reinterpret_cast<const float4*>(x_base + (size_t)s * 128);
    const float4* xp4 = reinterpret_cast<const float4*>(x_pa   + (size_t)s * 128);

    #pragma unroll 4
    for (int c = 0; c < 32; ++c) {
        const float4 x = xb4[c];
        #pragma unroll
        for (int j = 0; j < 8; ++j) {
            const float4 w = *reinterpret_cast<const float4*>(&bk[O_W1B + j * 132 + c * 4]);
            acc1[j] += w.x * x.x + w.y * x.y + w.z * x.z + w.w * x.w;
        }
        const float4 wo = *reinterpret_cast<const float4*>(&bk[O_WOUT + 64 + c * 4]);
        accout += wo.x * x.x + wo.y * x.y + wo.z * x.z + wo.w * x.w;
    }
    #pragma unroll 4
    for (int c = 0; c < 32; ++c) {
        const float4 x = xp4[c];
        #pragma unroll
        for (int j = 0; j < 8; ++j) {
            const float4 w = *reinterpret_cast<const float4*>(&bk[O_W1PA + j * 132 + c * 4]);
            acc1[8 + j] += w.x * x.x + w.y * x.y + w.z * x.z + w.w * x.w;
        }
        const float4 wo = *reinterpret_cast<const float4*>(&bk[O_WOUT + 192 + c * 4]);
        accout += wo.x * x.x + wo.y * x.y + wo.z * x.z + wo.w * x.w;
    }

    float l1c[32];
    #pragma unroll
    for (int k = 0; k < 16; ++k) {
        const float v = acc1[k];
        l1c[16 + k] = fminf(fmaxf(v, 0.0f), 1.0f);
        l1c[k] = fminf(v * v * (255.0f / 256.0f), 1.0f);
    }

    #pragma unroll 4
    for (int j = 0; j < 64; ++j) {
        float a = bk[O_B2 + j];
        #pragma unroll
        for (int k = 0; k < 32; k += 4) {
            const float4 w = *reinterpret_cast<const float4*>(&bk[O_W2 + j * 32 + k]);
            a += w.x * l1c[k] + w.y * l1c[k + 1] + w.z * l1c[k + 2] + w.w * l1c[k + 3];
        }
        a = fminf(fmaxf(a, 0.0f), 1.0f);
        a = a * a * (255.0f / 256.0f);
        accout += bk[O_WOUT + j] * a;
    }
    return accout;
}

// ---------------- main (sorted) kernel ---------------------------------------
__global__ __launch_bounds__(1024, 8)
void layerstacks_sorted(const float* __restrict__ x_base,
                        const float* __restrict__ x_pa,
                        const float* __restrict__ mobility,
                        const int*   __restrict__ ply,
                        const float* __restrict__ W1b,
                        const float* __restrict__ b1b,
                        const float* __restrict__ W1pa,
                        const float* __restrict__ b1pa,
                        const float* __restrict__ W2,
                        const float* __restrict__ b2,
                        const float* __restrict__ Wout,
                        const float* __restrict__ bout,
                        const int*   __restrict__ ws,
                        float* __restrict__ out, int B)
{
    __shared__ float lds[2 * BSTR];   // 36.6 KB -> 2 blocks/CU (thread-limited)
    const int* perm = ws + 16;
    const int tid = threadIdx.x;
    const int p0 = blockIdx.x * 1024;

    const int b0 = ply[perm[p0]] / 10;
    const int b1 = ply[perm[p0 + 1023]] / 10;

    stage_bucket(lds, b0, tid, W1b, b1b, W1pa, b1pa, W2, b2, Wout, bout);
    if (b1 != b0)
        stage_bucket(lds + BSTR, b1, tid, W1b, b1b, W1pa, b1pa, W2, b2, Wout, bout);
    __syncthreads();

    const int s = perm[p0 + tid];
    const int idx = ply[s] / 10;
    const float* bk = lds + (idx == b0 ? 0 : BSTR);
    const float mob = fminf(mobility[s] * (7.0f / 255.0f), 1.0f);

    out[s] = compute_sample(bk, x_base, x_pa, mob, s);
}

// ---------------- fallback (round-1 kernel, all 6 buckets in LDS) ------------
__global__ __launch_bounds__(1024, 1)
void layerstacks_fallback(const float* __restrict__ x_base,
                          const float* __restrict__ x_pa,
                          const float* __restrict__ mobility,
                          const int*   __restrict__ ply,
                          const float* __restrict__ W1b,
                          const float* __restrict__ b1b,
                          const float* __restrict__ W1pa,
                          const float* __restrict__ b1pa,
                          const float* __restrict__ W2,
                          const float* __restrict__ b2,
                          const float* __restrict__ Wout,
                          const float* __restrict__ bout,
                          float* __restrict__ out)
{
    __shared__ float lds[NB * BSTR];
    const int tid = threadIdx.x;
    for (int b = 0; b < NB; ++b)
        stage_bucket(lds + b * BSTR, b, tid, W1b, b1b, W1pa, b1pa, W2, b2, Wout, bout);
    __syncthreads();

    const int s = blockIdx.x * 1024 + tid;
    const int idx = ply[s] / 10;
    const float* bk = &lds[idx * BSTR];
    const float mob = fminf(mobility[s] * (7.0f / 255.0f), 1.0f);
    out[s] = compute_sample(bk, x_base, x_pa, mob, s);
}

extern "C" void kernel_launch(void* const* d_in, const int* in_sizes, int n_in,
                              void* d_out, int out_size, void* d_ws, size_t ws_size,
                              hipStream_t stream) {
    const float* x_base   = (const float*)d_in[0];
    const float* x_pa     = (const float*)d_in[1];
    const float* mobility = (const float*)d_in[2];
    const int*   ply      = (const int*)d_in[3];
    const float* W1b      = (const float*)d_in[4];
    const float* b1b      = (const float*)d_in[5];
    const float* W1pa     = (const float*)d_in[6];
    const float* b1pa     = (const float*)d_in[7];
    const float* W2       = (const float*)d_in[8];
    const float* b2       = (const float*)d_in[9];
    const float* Wout     = (const float*)d_in[10];
    const float* bout     = (const float*)d_in[11];
    float* out = (float*)d_out;

    const int B = in_sizes[3];            // 262144
    const int blocks = (B + 1023) / 1024; // 256

    const size_t ws_needed = (size_t)(16 + B) * sizeof(int);
    if (ws_size >= ws_needed) {
        int* ws = (int*)d_ws;
        k_zero<<<1, 64, 0, stream>>>(ws);
        k_hist<<<blocks, 1024, 0, stream>>>(ply, ws, B);
        k_scan<<<1, 64, 0, stream>>>(ws);
        k_scatter<<<blocks, 1024, 0, stream>>>(ply, ws, B);
        layerstacks_sorted<<<blocks, 1024, 0, stream>>>(
            x_base, x_pa, mobility, ply, W1b, b1b, W1pa, b1pa, W2, b2, Wout, bout,
            ws, out, B);
    } else {
        layerstacks_fallback<<<blocks, 1024, 0, stream>>>(
            x_base, x_pa, mobility, ply, W1b, b1b, W1pa, b1pa, W2, b2, Wout, bout, out);
    }
}

// Round 3
// 111.246 us; speedup vs baseline: 1.1926x; 1.1926x over previous
//
#include <hip/hip_runtime.h>

// LayerStacks round 3: bucket-sorted, 64-aligned bucket segments -> every wave
// is bucket-uniform -> bucket idx in SGPR (readfirstlane) -> ALL weight loads
// are scalar (s_load) broadcasts. No LDS in the main kernel at all.
//
// d_ws layout:
//   floats [0 .. WBLOB)            packed weights, 6 buckets x BSTRIDE
//   ints   [WBLOB .. WBLOB+16)     cnt[6] (pad to 8), cursor[6] (pad to 8)
//   ints   [WBLOB+16 .. +16+PADCAP) perm (bucket-sorted sample ids, -1 = pad)

#define NB 6
#define BSTRIDE 4544            // floats per bucket slot (16B-aligned)
#define O_W1T   0               // [c=0..31][j=0..7][q=0..3]  (c-major W1b)
#define O_WPAT  1024            // same for W1pa
#define O_MW1B  2048            // [8]  W1b[:,128] (mobility col)
#define O_MW1PA 2056            // [8]
#define O_B1B   2064            // [8]
#define O_B1PA  2072            // [8]
#define O_W2    2080            // [64][32] row-major
#define O_WOUT  4128            // [320]
#define O_B2    4448            // [64]
#define O_BOUT  4512            // [1]
#define WBLOB   (NB * BSTRIDE)  // 27264 floats

// ---------------- init: prefill perm with -1, zero counters, pack weights ----
__global__ __launch_bounds__(256)
void k_init(const float* __restrict__ W1b, const float* __restrict__ b1b,
            const float* __restrict__ W1pa, const float* __restrict__ b1pa,
            const float* __restrict__ W2, const float* __restrict__ b2,
            const float* __restrict__ Wout, const float* __restrict__ bout,
            float* __restrict__ wsF, int* __restrict__ wsI, int B)
{
    const int i0 = blockIdx.x * 256 + threadIdx.x;
    const int stride = gridDim.x * 256;
    const int padcap = B + NB * 64;
    int* perm = wsI + 16;

    for (int i = i0; i < padcap; i += stride) perm[i] = -1;
    if (i0 < 16) wsI[i0] = 0;

    // W1 transposed to c-major quads
    for (int e = i0; e < NB * 1024; e += stride) {
        int b = e >> 10, r = e & 1023;
        int c = r >> 5, j = (r >> 2) & 7, q = r & 3;
        int src = b * 1032 + j * 129 + c * 4 + q;
        wsF[b * BSTRIDE + O_W1T  + r] = W1b[src];
        wsF[b * BSTRIDE + O_WPAT + r] = W1pa[src];
    }
    for (int e = i0; e < NB * 8; e += stride) {
        int b = e >> 3, j = e & 7;
        wsF[b * BSTRIDE + O_MW1B  + j] = W1b[b * 1032 + j * 129 + 128];
        wsF[b * BSTRIDE + O_MW1PA + j] = W1pa[b * 1032 + j * 129 + 128];
        wsF[b * BSTRIDE + O_B1B   + j] = b1b[e];
        wsF[b * BSTRIDE + O_B1PA  + j] = b1pa[e];
    }
    for (int e = i0; e < NB * 2048; e += stride) {
        int b = e >> 11, r = e & 2047;
        wsF[b * BSTRIDE + O_W2 + r] = W2[e];
    }
    for (int e = i0; e < NB * 320; e += stride) {
        int b = e / 320, r = e - b * 320;
        wsF[b * BSTRIDE + O_WOUT + r] = Wout[e];
    }
    for (int e = i0; e < NB * 64; e += stride) {
        int b = e >> 6, r = e & 63;
        wsF[b * BSTRIDE + O_B2 + r] = b2[e];
    }
    for (int e = i0; e < NB; e += stride)
        wsF[e * BSTRIDE + O_BOUT] = bout[e];
}

// ---------------- histogram --------------------------------------------------
__global__ __launch_bounds__(256)
void k_hist(const int* __restrict__ ply, int* __restrict__ wsI, int B) {
    __shared__ int lh[NB];
    const int tid = threadIdx.x;
    if (tid < NB) lh[tid] = 0;
    __syncthreads();
    const int s = blockIdx.x * 256 + tid;
    if (s < B) atomicAdd(&lh[ply[s] / 10], 1);
    __syncthreads();
    if (tid < NB) atomicAdd(&wsI[tid], lh[tid]);
}

// ---------------- scan: 64-aligned bucket bases ------------------------------
__global__ void k_scan(int* __restrict__ wsI) {
    if (threadIdx.x == 0) {
        int base = 0;
        for (int b = 0; b < NB; ++b) {
            wsI[8 + b] = base;                      // cursor starts at base
            base += (wsI[b] + 63) & ~63;            // pad segment to 64
        }
    }
}

// ---------------- scatter ----------------------------------------------------
__global__ __launch_bounds__(256)
void k_scatter(const int* __restrict__ ply, int* __restrict__ wsI, int B) {
    __shared__ int lh[NB];
    __shared__ int lbase[NB];
    int* cursor = wsI + 8;
    int* perm   = wsI + 16;
    const int tid = threadIdx.x;
    if (tid < NB) lh[tid] = 0;
    __syncthreads();
    const int s = blockIdx.x * 256 + tid;
    int b = 0, lpos = 0;
    if (s < B) { b = ply[s] / 10; lpos = atomicAdd(&lh[b], 1); }
    __syncthreads();
    if (tid < NB) lbase[tid] = atomicAdd(&cursor[tid], lh[tid]);
    __syncthreads();
    if (s < B) perm[lbase[b] + lpos] = s;
}

// ---------------- main: wave-uniform bucket, scalar weights ------------------
__global__ __launch_bounds__(256, 4)
void layerstacks_main(const float* __restrict__ x_base,
                      const float* __restrict__ x_pa,
                      const float* __restrict__ mobility,
                      const int*   __restrict__ ply,
                      const float* __restrict__ wsF,
                      const int*   __restrict__ wsI,
                      float* __restrict__ out, int B)
{
    const int padcap = B + NB * 64;
    const int pos = blockIdx.x * 256 + threadIdx.x;   // wave = 64 consecutive pos
    const int* perm = wsI + 16;

    int s = (pos < padcap) ? perm[pos] : -1;
    const int s0 = __builtin_amdgcn_readfirstlane(s);
    if (s0 < 0) return;                               // whole wave is padding

    // bucket is wave-uniform by construction (64-aligned segments)
    const int bu = __builtin_amdgcn_readfirstlane(ply[s0] / 10);
    const float* __restrict__ wp = wsF + bu * BSTRIDE;

    const bool valid = (s >= 0);
    const int su = valid ? s : s0;                    // safe row for pad lanes
    const float mob = fminf(mobility[su] * (7.0f / 255.0f), 1.0f);

    // L1 accumulators seeded with bias + mobility column
    float acc1[16];
    #pragma unroll
    for (int j = 0; j < 8; ++j)
        acc1[j] = wp[O_B1B + j] + wp[O_MW1B + j] * mob;
    #pragma unroll
    for (int j = 0; j < 8; ++j)
        acc1[8 + j] = wp[O_B1PA + j] + wp[O_MW1PA + j] * mob;

    float accout = wp[O_BOUT];

    const float4* __restrict__ xb4 = reinterpret_cast<const float4*>(x_base + (size_t)su * 128);
    const float4* __restrict__ xp4 = reinterpret_cast<const float4*>(x_pa   + (size_t)su * 128);

    // x_base stream: feeds L1-base rows + Wout[64:192]
    #pragma unroll 4
    for (int c = 0; c < 32; ++c) {
        const float4 x = xb4[c];
        #pragma unroll
        for (int j = 0; j < 8; ++j) {
            const float4 w = *reinterpret_cast<const float4*>(wp + O_W1T + c * 32 + j * 4);
            acc1[j] += w.x * x.x + w.y * x.y + w.z * x.z + w.w * x.w;
        }
        const float4 wo = *reinterpret_cast<const float4*>(wp + O_WOUT + 64 + c * 4);
        accout += wo.x * x.x + wo.y * x.y + wo.z * x.z + wo.w * x.w;
    }
    // x_pa stream: feeds L1-pa rows + Wout[192:320]
    #pragma unroll 4
    for (int c = 0; c < 32; ++c) {
        const float4 x = xp4[c];
        #pragma unroll
        for (int j = 0; j < 8; ++j) {
            const float4 w = *reinterpret_cast<const float4*>(wp + O_WPAT + c * 32 + j * 4);
            acc1[8 + j] += w.x * x.x + w.y * x.y + w.z * x.z + w.w * x.w;
        }
        const float4 wo = *reinterpret_cast<const float4*>(wp + O_WOUT + 192 + c * 4);
        accout += wo.x * x.x + wo.y * x.y + wo.z * x.z + wo.w * x.w;
    }

    // l1c = clip([l1^2 * 255/256, l1], 0, 1)
    float l1c[32];
    #pragma unroll
    for (int k = 0; k < 16; ++k) {
        const float v = acc1[k];
        l1c[16 + k] = fminf(fmaxf(v, 0.0f), 1.0f);
        l1c[k] = fminf(v * v * (255.0f / 256.0f), 1.0f);
    }

    // L2 (64x32) fused with Wout[0:64]
    #pragma unroll 4
    for (int j = 0; j < 64; ++j) {
        float a = wp[O_B2 + j];
        #pragma unroll
        for (int kq = 0; kq < 8; ++kq) {
            const float4 w = *reinterpret_cast<const float4*>(wp + O_W2 + j * 32 + kq * 4);
            a += w.x * l1c[kq * 4] + w.y * l1c[kq * 4 + 1]
               + w.z * l1c[kq * 4 + 2] + w.w * l1c[kq * 4 + 3];
        }
        a = fminf(fmaxf(a, 0.0f), 1.0f);
        a = a * a * (255.0f / 256.0f);
        accout += wp[O_WOUT + j] * a;
    }

    if (valid) out[s] = accout;
}

// ---------------- fallback (round-1 style, self-contained) -------------------
#define FB_BSTR 4580
#define FO_W1B  0
#define FO_W1PA 1056
#define FO_W2   2112
#define FO_WOUT 4160
#define FO_B1B  4480
#define FO_B1PA 4488
#define FO_B2   4496
#define FO_BOUT 4560

__global__ __launch_bounds__(1024, 1)
void layerstacks_fallback(const float* __restrict__ x_base,
                          const float* __restrict__ x_pa,
                          const float* __restrict__ mobility,
                          const int*   __restrict__ ply,
                          const float* __restrict__ W1b,
                          const float* __restrict__ b1b,
                          const float* __restrict__ W1pa,
                          const float* __restrict__ b1pa,
                          const float* __restrict__ W2,
                          const float* __restrict__ b2,
                          const float* __restrict__ Wout,
                          const float* __restrict__ bout,
                          float* __restrict__ out)
{
    __shared__ float lds[NB * FB_BSTR];
    const int tid = threadIdx.x;
    for (int e = tid; e < NB * 1032; e += 1024) {
        int b = e / 1032, r = e - b * 1032;
        int row = r / 129, col = r - row * 129;
        lds[b * FB_BSTR + FO_W1B + row * 132 + col] = W1b[e];
        lds[b * FB_BSTR + FO_W1PA + row * 132 + col] = W1pa[e];
    }
    for (int e = tid; e < NB * 2048; e += 1024) {
        int b = e >> 11, r = e & 2047;
        lds[b * FB_BSTR + FO_W2 + r] = W2[e];
    }
    for (int e = tid; e < NB * 320; e += 1024) {
        int b = e / 320, r = e - b * 320;
        lds[b * FB_BSTR + FO_WOUT + r] = Wout[e];
    }
    if (tid < NB * 8) {
        int b = tid >> 3, r = tid & 7;
        lds[b * FB_BSTR + FO_B1B + r]  = b1b[tid];
        lds[b * FB_BSTR + FO_B1PA + r] = b1pa[tid];
    }
    for (int e = tid; e < NB * 64; e += 1024) {
        int b = e >> 6, r = e & 63;
        lds[b * FB_BSTR + FO_B2 + r] = b2[e];
    }
    if (tid < NB) lds[tid * FB_BSTR + FO_BOUT] = bout[tid];
    __syncthreads();

    const int s = blockIdx.x * 1024 + tid;
    const int idx = ply[s] / 10;
    const float* bk = &lds[idx * FB_BSTR];
    const float mob = fminf(mobility[s] * (7.0f / 255.0f), 1.0f);

    float acc1[16];
    #pragma unroll
    for (int j = 0; j < 8; ++j)
        acc1[j] = bk[FO_B1B + j] + bk[FO_W1B + j * 132 + 128] * mob;
    #pragma unroll
    for (int j = 0; j < 8; ++j)
        acc1[8 + j] = bk[FO_B1PA + j] + bk[FO_W1PA + j * 132 + 128] * mob;
    float accout = bk[FO_BOUT];

    const float4* xb4 = reinterpret_cast<const float4*>(x_base + (size_t)s * 128);
    const float4* xp4 = reinterpret_cast<const float4*>(x_pa   + (size_t)s * 128);
    #pragma unroll 4
    for (int c = 0; c < 32; ++c) {
        const float4 x = xb4[c];
        #pragma unroll
        for (int j = 0; j < 8; ++j) {
            const float4 w = *reinterpret_cast<const float4*>(&bk[FO_W1B + j * 132 + c * 4]);
            acc1[j] += w.x * x.x + w.y * x.y + w.z * x.z + w.w * x.w;
        }
        const float4 wo = *reinterpret_cast<const float4*>(&bk[FO_WOUT + 64 + c * 4]);
        accout += wo.x * x.x + wo.y * x.y + wo.z * x.z + wo.w * x.w;
    }
    #pragma unroll 4
    for (int c = 0; c < 32; ++c) {
        const float4 x = xp4[c];
        #pragma unroll
        for (int j = 0; j < 8; ++j) {
            const float4 w = *reinterpret_cast<const float4*>(&bk[FO_W1PA + j * 132 + c * 4]);
            acc1[8 + j] += w.x * x.x + w.y * x.y + w.z * x.z + w.w * x.w;
        }
        const float4 wo = *reinterpret_cast<const float4*>(&bk[FO_WOUT + 192 + c * 4]);
        accout += wo.x * x.x + wo.y * x.y + wo.z * x.z + wo.w * x.w;
    }
    float l1c[32];
    #pragma unroll
    for (int k = 0; k < 16; ++k) {
        const float v = acc1[k];
        l1c[16 + k] = fminf(fmaxf(v, 0.0f), 1.0f);
        l1c[k] = fminf(v * v * (255.0f / 256.0f), 1.0f);
    }
    #pragma unroll 4
    for (int j = 0; j < 64; ++j) {
        float a = bk[FO_B2 + j];
        #pragma unroll
        for (int k = 0; k < 32; k += 4) {
            const float4 w = *reinterpret_cast<const float4*>(&bk[FO_W2 + j * 32 + k]);
            a += w.x * l1c[k] + w.y * l1c[k + 1] + w.z * l1c[k + 2] + w.w * l1c[k + 3];
        }
        a = fminf(fmaxf(a, 0.0f), 1.0f);
        a = a * a * (255.0f / 256.0f);
        accout += bk[FO_WOUT + j] * a;
    }
    out[s] = accout;
}

extern "C" void kernel_launch(void* const* d_in, const int* in_sizes, int n_in,
                              void* d_out, int out_size, void* d_ws, size_t ws_size,
                              hipStream_t stream) {
    const float* x_base   = (const float*)d_in[0];
    const float* x_pa     = (const float*)d_in[1];
    const float* mobility = (const float*)d_in[2];
    const int*   ply      = (const int*)d_in[3];
    const float* W1b      = (const float*)d_in[4];
    const float* b1b      = (const float*)d_in[5];
    const float* W1pa     = (const float*)d_in[6];
    const float* b1pa     = (const float*)d_in[7];
    const float* W2       = (const float*)d_in[8];
    const float* b2       = (const float*)d_in[9];
    const float* Wout     = (const float*)d_in[10];
    const float* bout     = (const float*)d_in[11];
    float* out = (float*)d_out;

    const int B = in_sizes[3];                      // 262144
    const int padcap = B + NB * 64;
    const size_t ws_needed = (size_t)(WBLOB + 16 + padcap) * sizeof(int);

    if (ws_size >= ws_needed) {
        float* wsF = (float*)d_ws;
        int*   wsI = (int*)d_ws + WBLOB;

        const int blocks256 = (B + 255) / 256;      // 1024
        k_init<<<256, 256, 0, stream>>>(W1b, b1b, W1pa, b1pa, W2, b2, Wout, bout,
                                        wsF, wsI, B);
        k_hist<<<blocks256, 256, 0, stream>>>(ply, wsI, B);
        k_scan<<<1, 64, 0, stream>>>(wsI);
        k_scatter<<<blocks256, 256, 0, stream>>>(ply, wsI, B);

        const int waves = padcap / 64;              // B multiple of 64
        const int mblocks = (waves + 3) / 4;        // 4 waves per block
        layerstacks_main<<<mblocks, 256, 0, stream>>>(
            x_base, x_pa, mobility, ply, wsF, wsI, out, B);
    } else {
        layerstacks_fallback<<<B / 1024, 1024, 0, stream>>>(
            x_base, x_pa, mobility, ply, W1b, b1b, W1pa, b1pa, W2, b2, Wout, bout, out);
    }
}